// Round 12
// baseline (180.049 us; speedup 1.0000x reference)
//
#include <hip/hip_runtime.h>
#include <hip/hip_bf16.h>

#define N_NODES 50000
#define N_EDGES 800000
#define DIM 64
#define NHEAD 2
#define HD 128     // NHEAD * DIM
#define NCOL 448   // 128 q + 128 k + 128 vc + 64 skipc
#define MAXDEG 64  // ELL row stride; max Poisson(16) deg over 50k nodes ~ 45

#define NBIN 196    // bins of 256 nodes: 196*256 = 50176 >= 50000
#define BCAP 6144   // bin capacity; lambda=4082, +32 sigma
#define ACH 2048    // edges per bin-block
#define BIN_BLKS 391 // ceil(800000/2048)

#define PREP_B 112  // 448*64/256
#define PROJ_B 782  // ceil(50000/64)
#define ATTN_B 3125 // 50000/16 — 4 nodes per wave, 16 lanes (2 edge-slots x 8 ch) per node

// q pre-scale: 1/sqrt(64) * 1/ln(2)  -> logits are in exp2 domain
#define QSCALE 0.18033688011112042f

typedef short bf16x8 __attribute__((ext_vector_type(8)));
typedef float f32x16 __attribute__((ext_vector_type(16)));
typedef float f32x2 __attribute__((ext_vector_type(2)));

__device__ __forceinline__ unsigned short f2bf(float f) {
    unsigned u = __float_as_uint(f);
    unsigned r = (u + 0x7fffu + ((u >> 16) & 1u)) >> 16;   // RNE
    return (unsigned short)r;
}
// fp8 e4m3 HW converts (gfx950 OCP): encode f32 -> 1 byte
__device__ __forceinline__ unsigned char f2fp8(float f) {
    int r = __builtin_amdgcn_cvt_pk_fp8_f32(f, f, 0, false);
    return (unsigned char)(r & 0xff);
}
// packed bf16 pair (u32) -> f32x2
__device__ __forceinline__ f32x2 bf2x2(unsigned v) {
    f32x2 r;
    r[0] = __uint_as_float(v << 16);
    r[1] = __uint_as_float(v & 0xffff0000u);
    return r;
}
// x + dpp_shuffled(x): pure-VALU cross-lane add (no ds_bpermute / lgkmcnt)
template <int CTRL>
__device__ __forceinline__ float dppadd(float x) {
    int m = __builtin_amdgcn_update_dpp(0, __float_as_int(x), CTRL, 0xf, 0xf, true);
    return x + __int_as_float(m);
}

// ------- merged: folded-weight prep ∥ streamlined edge binning -------
__global__ __launch_bounds__(256) void k_pb(
    const int* __restrict__ ei,
    const float* __restrict__ Wq, const float* __restrict__ bq,
    const float* __restrict__ Wk, const float* __restrict__ bk,
    const float* __restrict__ Wv, const float* __restrict__ bv,
    const float* __restrict__ Wskip, const float* __restrict__ bskip,
    const float* __restrict__ Wc, const float* __restrict__ bc,
    unsigned short* __restrict__ WallT, float* __restrict__ ball,
    int* __restrict__ bincnt, unsigned* __restrict__ bins,
    double* __restrict__ sacc)
{
    const int t = threadIdx.x;
    if (blockIdx.x < PREP_B) {
        if (blockIdx.x == 0) { sacc[t] = 0.0; sacc[256 + t] = 0.0; }
        int gid = blockIdx.x * 256 + t;   // 0..28671
        const int j = gid >> 6;   // output column 0..447
        const int d = gid & 63;   // k index
        float w, bb;
        if (j < 128) {
            w = Wq[d * HD + j] * QSCALE;
            bb = bq[j] * QSCALE;
        } else if (j < 256) {
            int jj = j - 128;
            w = Wk[d * HD + jj];
            bb = bk[jj];
        } else if (j < 384) {
            int jj = j - 256;
            int h = jj >> 6, jc = jj & 63;
            float s = 0.f, sb = 0.f;
            for (int c = 0; c < 64; c++) {
                float wc = Wc[(h * 64 + c) * DIM + jc];
                s  += Wv[d * HD + h * 64 + c] * wc;
                sb += bv[h * 64 + c] * wc;
            }
            w = s; bb = sb;
        } else {
            int jj = j - 384;
            float s = 0.f, sb = bc[jj];
            for (int c = 0; c < HD; c++) {
                float wc = Wc[c * DIM + jj];
                s  += Wskip[d * HD + c] * wc;
                sb += bskip[c] * wc;
            }
            w = s; bb = sb;
        }
        WallT[gid] = f2bf(w);
        if (d == 0) ball[j] = bb;
        return;
    }
    // ---- binning: count+rank, reserve, scatter ----
    __shared__ int hist[256];
    __shared__ int gbase[256];
    const int e0 = (blockIdx.x - PREP_B) * ACH;
    hist[t] = 0;
    __syncthreads();
    unsigned pk8[8];
    int bin8[8], sl8[8];
#pragma unroll
    for (int k = 0; k < 8; k++) {
        int e = e0 + t + k * 256;
        if (e < N_EDGES) {
            int src = ei[e];
            int d = ei[N_EDGES + e];
            int bin = d >> 8;
            pk8[k] = (unsigned)(((d & 255) << 16) | src);
            bin8[k] = bin;
            sl8[k] = atomicAdd(&hist[bin], 1);
        } else {
            bin8[k] = -1;
        }
    }
    __syncthreads();
    if (t < NBIN) {
        int h = hist[t];
        if (h > 0) gbase[t] = atomicAdd(&bincnt[t], h);
    }
    __syncthreads();
#pragma unroll
    for (int k = 0; k < 8; k++) {
        int bin = bin8[k];
        if (bin >= 0) {
            int pos = gbase[bin] + sl8[k];
            if (pos < BCAP) bins[(size_t)bin * BCAP + pos] = pk8[k];
        }
    }
}

// ------- MFMA projection GEMM (LDS-staged coalesced stores) — split from k_ep ------
__global__ __launch_bounds__(256) void k_proj(
    const float* __restrict__ x,
    const unsigned short* __restrict__ WallT, const float* __restrict__ ball,
    unsigned short* __restrict__ q, unsigned char* __restrict__ kv,
    float* __restrict__ skipc)
{
    __shared__ __align__(16) unsigned char smem[49152];
    const int blk = blockIdx.x;
    const int t = threadIdx.x;
    unsigned short* q_s = (unsigned short*)smem;     // [64][128] u16 16KB
    unsigned char* kv_s = smem + 16384;              // [64][256] u8  16KB
    float* sk_s = (float*)(smem + 32768);            // [64][64]  f32 16KB

    const int w = t >> 6;
    const int lane = t & 63;
    const int col = lane & 31;
    const int khalf = lane >> 5;
    const int nloc0 = (w >> 1) * 32;
    const int n0 = blk * 64 + nloc0;
    const int ct0 = (w & 1) * 7;
    const int rowbase = 4 * khalf;

    int nread = n0 + col; if (nread >= N_NODES) nread = N_NODES - 1;
    const float* ap = x + (size_t)nread * 64 + khalf * 8;
    bf16x8 afrag[4];
#pragma unroll
    for (int kk = 0; kk < 4; kk++) {
        float4 xa = *((const float4*)(ap + kk * 16));
        float4 xb4 = *((const float4*)(ap + kk * 16 + 4));
        bf16x8 f;
        f[0] = (short)f2bf(xa.x); f[1] = (short)f2bf(xa.y);
        f[2] = (short)f2bf(xa.z); f[3] = (short)f2bf(xa.w);
        f[4] = (short)f2bf(xb4.x); f[5] = (short)f2bf(xb4.y);
        f[6] = (short)f2bf(xb4.z); f[7] = (short)f2bf(xb4.w);
        afrag[kk] = f;
    }

    for (int tt = 0; tt < 7; tt++) {
        const int gc = (ct0 + tt) * 32 + col;
        const float b = ball[gc];
        f32x16 acc;
#pragma unroll
        for (int r = 0; r < 16; r++) acc[r] = b;
        const unsigned short* bp = WallT + (size_t)gc * 64 + khalf * 8;
#pragma unroll
        for (int kk = 0; kk < 4; kk++) {
            bf16x8 bfrag = *((const bf16x8*)(bp + kk * 16));
            acc = __builtin_amdgcn_mfma_f32_32x32x16_bf16(afrag[kk], bfrag, acc, 0, 0, 0);
        }
        if (gc < 128) {
#pragma unroll
            for (int r = 0; r < 16; r++) {
                int nl = nloc0 + rowbase + (r & 3) + 8 * (r >> 2);
                q_s[nl * 128 + gc] = f2bf(acc[r]);
            }
        } else if (gc < 384) {
            int ch = gc - 128;           // 0..255 (K: 0..127, V: 128..255)
            int half = ch >> 7;          // 0=K, 1=V
            int cc = ch & 127;
            int h = cc >> 6, c = cc & 63;
            int pos = half * 128 + ((c >> 3) << 4) + (h << 3) + (c & 7);
#pragma unroll
            for (int r = 0; r < 16; r++) {
                int nl = nloc0 + rowbase + (r & 3) + 8 * (r >> 2);
                kv_s[nl * 256 + pos] = f2fp8(acc[r]);
            }
        } else {
            int c = gc - 384;
#pragma unroll
            for (int r = 0; r < 16; r++) {
                int nl = nloc0 + rowbase + (r & 3) + 8 * (r >> 2);
                sk_s[nl * 64 + c] = acc[r];
            }
        }
    }
    __syncthreads();
    // ---- coalesced flush ----
    const size_t nbase = (size_t)blk * 64;
    const int nrem = (int)(N_NODES - nbase);      // >=1 always
    {   // q bf16: [64][128] u16 = 1024 uint4 (16 per node)
        const uint4* s4 = (const uint4*)q_s;
        uint4* g4 = (uint4*)(q + nbase * HD);
        int lim = nrem >= 64 ? 1024 : nrem * 16;
#pragma unroll
        for (int kk = 0; kk < 4; kk++) {
            int i = t + kk * 256;
            if (i < lim) g4[i] = s4[i];
        }
    }
    {   // kv: [64][256] u8 = 1024 uint4 (16 per node)
        const uint4* s4 = (const uint4*)kv_s;
        uint4* g4 = (uint4*)(kv + nbase * 256);
        int lim = nrem >= 64 ? 1024 : nrem * 16;
#pragma unroll
        for (int kk = 0; kk < 4; kk++) {
            int i = t + kk * 256;
            if (i < lim) g4[i] = s4[i];
        }
    }
    {   // skipc: [64][64] f32 = 1024 float4 (16 per node)
        const float4* s4 = (const float4*)sk_s;
        float4* g4 = (float4*)(skipc + nbase * DIM);
        int lim = nrem >= 64 ? 1024 : nrem * 16;
#pragma unroll
        for (int kk = 0; kk < 4; kk++) {
            int i = t + kk * 256;
            if (i < lim) g4[i] = s4[i];
        }
    }
}

// ------- bin -> ELL unpack (u16, deg written directly) — split from k_ep -------
__global__ __launch_bounds__(256) void k_ell(
    const int* __restrict__ bincnt, const unsigned* __restrict__ bins,
    int* __restrict__ deg, unsigned short* __restrict__ elist)
{
    __shared__ int nodecnt[256];
    const int bin = blockIdx.x;
    const int t = threadIdx.x;
    nodecnt[t] = 0;
    __syncthreads();
    int cnt = bincnt[bin]; if (cnt > BCAP) cnt = BCAP;
    const unsigned* bp = bins + (size_t)bin * BCAP;
    for (int i = t; i < cnt; i += 256) {
        unsigned p = bp[i];
        int local = p >> 16;
        int src = p & 0xffff;
        int sl = atomicAdd(&nodecnt[local], 1);
        if (sl < MAXDEG)
            elist[((size_t)((bin << 8) | local)) * MAXDEG + sl] = (unsigned short)src;
    }
    __syncthreads();
    int node = (bin << 8) + t;
    if (node < N_NODES) {
        int dgv = nodecnt[t];
        deg[node] = dgv > MAXDEG ? MAXDEG : dgv;
    }
}

// -------- fused attention: 16 lanes/node = 2 edge-slots x 8 ch-lanes, 4 nodes/wave --
// (byte-identical to round 11's passing kernel)
__global__ __launch_bounds__(256) void k_attn(
    const unsigned short* __restrict__ q, const unsigned char* __restrict__ kv,
    const float* __restrict__ skipc,
    const int* __restrict__ deg, const unsigned short* __restrict__ elist,
    float* __restrict__ out, double* __restrict__ sacc)
{
    const int w = threadIdx.x >> 6;
    const int lane = threadIdx.x & 63;
    const int e = (lane >> 3) & 1;   // edge slot 0/1
    const int j = lane & 7;          // channels 8j..8j+7 of each head
    const int n = blockIdx.x * 16 + w * 4 + (lane >> 4);
    const bool nvalid = n < N_NODES;
    const int nn = nvalid ? n : N_NODES - 1;

    const uint2 E = *((const uint2*)(elist + (size_t)nn * MAXDEG + (lane & 15) * 4));
    int dg = nvalid ? deg[nn] : 0;
    if (dg > MAXDEG) dg = MAXDEG;
    int dgmax = dg;   // wave max over 4 nodes
    {
        int o1 = __shfl_xor(dgmax, 16, 64); if (o1 > dgmax) dgmax = o1;
        int o2 = __shfl_xor(dgmax, 32, 64); if (o2 > dgmax) dgmax = o2;
    }

    const uint4* qp4 = (const uint4*)(q + (size_t)nn * HD);
    const uint4 Qa = qp4[j], Qb = qp4[8 + j];
    f32x2 q0[4], q1[4];
    q0[0] = bf2x2(Qa.x); q0[1] = bf2x2(Qa.y); q0[2] = bf2x2(Qa.z); q0[3] = bf2x2(Qa.w);
    q1[0] = bf2x2(Qb.x); q1[1] = bf2x2(Qb.y); q1[2] = bf2x2(Qb.z); q1[3] = bf2x2(Qb.w);

    f32x2 acc0[4], acc1[4];
#pragma unroll
    for (int i = 0; i < 4; i++) {
        acc0[i] = (f32x2){0.f, 0.f};
        acc1[i] = (f32x2){0.f, 0.f};
    }
    float l0 = 0.f, l1 = 0.f;

    if (dgmax > 0) {
        int sd0 = __shfl((int)E.x, (lane & 48), 64);
        unsigned v0 = e ? (((unsigned)sd0) >> 16) : (((unsigned)sd0) & 0xffffu);
        int s0 = (e < dg) ? (int)v0 : 0;
        const uint4* kp0 = (const uint4*)(kv + (size_t)s0 * 256);
        uint4 K = kp0[j], V = kp0[8 + j];

        for (int b = 0; b < dgmax; b += 2) {
            uint4 Kn = {0, 0, 0, 0}, Vn = {0, 0, 0, 0};
            const int bn = b + 2;
            if (bn < dgmax) {
                unsigned dwd = ((bn >> 1) & 1) ? E.y : E.x;
                int sd = __shfl((int)dwd, (lane & 48) | (bn >> 2), 64);
                unsigned v16 = e ? (((unsigned)sd) >> 16) : (((unsigned)sd) & 0xffffu);
                int sn = ((bn + e) < dg) ? (int)v16 : 0;
                const uint4* kpn = (const uint4*)(kv + (size_t)sn * 256);
                Kn = kpn[j]; Vn = kpn[8 + j];
            }
            const bool valid = (b + e) < dg;
            f32x2 p0v = q0[0] * __builtin_amdgcn_cvt_pk_f32_fp8(K.x, false);
            p0v += q0[1] * __builtin_amdgcn_cvt_pk_f32_fp8(K.x, true);
            p0v += q0[2] * __builtin_amdgcn_cvt_pk_f32_fp8(K.y, false);
            p0v += q0[3] * __builtin_amdgcn_cvt_pk_f32_fp8(K.y, true);
            f32x2 p1v = q1[0] * __builtin_amdgcn_cvt_pk_f32_fp8(K.z, false);
            p1v += q1[1] * __builtin_amdgcn_cvt_pk_f32_fp8(K.z, true);
            p1v += q1[2] * __builtin_amdgcn_cvt_pk_f32_fp8(K.w, false);
            p1v += q1[3] * __builtin_amdgcn_cvt_pk_f32_fp8(K.w, true);
            float p0 = p0v[0] + p0v[1];
            float p1 = p1v[0] + p1v[1];
            p0 = dppadd<0xB1>(p0);  p1 = dppadd<0xB1>(p1);
            p0 = dppadd<0x4E>(p0);  p1 = dppadd<0x4E>(p1);
            p0 = dppadd<0x141>(p0); p1 = dppadd<0x141>(p1);
            float w0 = valid ? __builtin_amdgcn_exp2f(p0) : 0.f;
            float w1 = valid ? __builtin_amdgcn_exp2f(p1) : 0.f;
            l0 += w0; l1 += w1;
            f32x2 w0v = {w0, w0}, w1v = {w1, w1};
            acc0[0] += w0v * __builtin_amdgcn_cvt_pk_f32_fp8(V.x, false);
            acc0[1] += w0v * __builtin_amdgcn_cvt_pk_f32_fp8(V.x, true);
            acc0[2] += w0v * __builtin_amdgcn_cvt_pk_f32_fp8(V.y, false);
            acc0[3] += w0v * __builtin_amdgcn_cvt_pk_f32_fp8(V.y, true);
            acc1[0] += w1v * __builtin_amdgcn_cvt_pk_f32_fp8(V.z, false);
            acc1[1] += w1v * __builtin_amdgcn_cvt_pk_f32_fp8(V.z, true);
            acc1[2] += w1v * __builtin_amdgcn_cvt_pk_f32_fp8(V.w, false);
            acc1[3] += w1v * __builtin_amdgcn_cvt_pk_f32_fp8(V.w, true);
            K = Kn; V = Vn;
        }
    }

    // ---- merge the two edge slots (lane bit 3) ----
    l0 = dppadd<0x140>(l0);
    l1 = dppadd<0x140>(l1);
    float* a0 = (float*)acc0;
    float* a1 = (float*)acc1;
#pragma unroll
    for (int i = 0; i < 8; i++) {
        a0[i] += __shfl_xor(a0[i], 8, 64);
        a1[i] += __shfl_xor(a1[i], 8, 64);
    }

    const float inv0 = 1.f / (l0 + 1e-16f), inv1 = 1.f / (l1 + 1e-16f);
    const float4 sk4 = ((const float4*)(skipc + (size_t)nn * DIM))[2 * j + e];
    const int cb = e * 4;
    float o0 = a0[cb + 0] * inv0 + a1[cb + 0] * inv1 + sk4.x;
    float o1 = a0[cb + 1] * inv0 + a1[cb + 1] * inv1 + sk4.y;
    float o2 = a0[cb + 2] * inv0 + a1[cb + 2] * inv1 + sk4.z;
    float o3 = a0[cb + 3] * inv0 + a1[cb + 3] * inv1 + sk4.w;
    if (nvalid) {
        float4 r = {o0, o1, o2, o3};
        ((float4*)(out + (size_t)n * DIM))[2 * j + e] = r;
    }
    float s_ = 0.f, ss = 0.f;
    if (nvalid) {
        s_ = o0 + o1 + o2 + o3;
        ss = o0 * o0 + o1 * o1 + o2 * o2 + o3 * o3;
    }
    s_ = dppadd<0xB1>(s_);  ss = dppadd<0xB1>(ss);
    s_ = dppadd<0x4E>(s_);  ss = dppadd<0x4E>(ss);
    s_ = dppadd<0x141>(s_); ss = dppadd<0x141>(ss);
    s_ = dppadd<0x140>(s_); ss = dppadd<0x140>(ss);
    s_ += __shfl_xor(s_, 16, 64);
    ss += __shfl_xor(ss, 16, 64);
    s_ += __shfl_xor(s_, 32, 64);
    ss += __shfl_xor(ss, 32, 64);
    if (lane == 0) {
        int slot = (blockIdx.x * 4 + w) & 255;
        atomicAdd(&sacc[slot], (double)s_);
        atomicAdd(&sacc[256 + slot], (double)ss);
    }
}

// ---------------- graph layernorm + gamma/beta (reduces sacc per block) --------
__global__ __launch_bounds__(256) void k_norm(
    float* __restrict__ out, const double* __restrict__ sacc,
    const float* __restrict__ gamma, const float* __restrict__ beta)
{
    const int t = threadIdx.x;
    __shared__ double red[8];
    double s = sacc[t];
    double ss = sacc[256 + t];
#pragma unroll
    for (int off = 32; off > 0; off >>= 1) {
        s  += __shfl_down(s, off);
        ss += __shfl_down(ss, off);
    }
    int wv = t >> 6;
    if ((t & 63) == 0) { red[wv * 2] = s; red[wv * 2 + 1] = ss; }
    __syncthreads();
    double S  = red[0] + red[2] + red[4] + red[6];
    double SS = red[1] + red[3] + red[5] + red[7];
    const double cnt = (double)N_NODES * (double)DIM;
    double mean = S / cnt;
    double var  = SS / cnt - mean * mean;
    if (var < 0.0) var = 0.0;
    float mf = (float)mean;
    float inv = 1.0f / ((float)sqrt(var) + 1e-5f);
    int i = blockIdx.x * 256 + t;
    if (i >= N_NODES * DIM / 4) return;
    float4 v = ((const float4*)out)[i];
    float4 gv = ((const float4*)gamma)[i & 15];
    float4 bv2 = ((const float4*)beta)[i & 15];
    v.x = (v.x - mf) * inv * gv.x + bv2.x;
    v.y = (v.y - mf) * inv * gv.y + bv2.y;
    v.z = (v.z - mf) * inv * gv.z + bv2.z;
    v.w = (v.w - mf) * inv * gv.w + bv2.w;
    ((float4*)out)[i] = v;
}

extern "C" void kernel_launch(void* const* d_in, const int* in_sizes, int n_in,
                              void* d_out, int out_size, void* d_ws, size_t ws_size,
                              hipStream_t stream) {
    const float* x     = (const float*)d_in[0];
    const int*   ei    = (const int*)d_in[1];
    const float* Wq    = (const float*)d_in[2];
    const float* bq    = (const float*)d_in[3];
    const float* Wk    = (const float*)d_in[4];
    const float* bk    = (const float*)d_in[5];
    const float* Wv    = (const float*)d_in[6];
    const float* bv    = (const float*)d_in[7];
    const float* Wsk   = (const float*)d_in[8];
    const float* bsk   = (const float*)d_in[9];
    const float* Wc    = (const float*)d_in[10];
    const float* bc    = (const float*)d_in[11];
    const float* gamma = (const float*)d_in[12];
    const float* beta  = (const float*)d_in[13];
    float* out = (float*)d_out;

    // ws layout (sacc first for 8B alignment)
    double* sacc = (double*)d_ws;                            // [512] f64 stat slots
    unsigned short* q = (unsigned short*)(sacc + 512);       // [N,128] bf16
    unsigned char* kv = (unsigned char*)(q + (size_t)N_NODES * HD); // [N,256] fp8
    float* skipc = (float*)(kv + (size_t)N_NODES * 256);     // [N,64]  f32
    unsigned short* WallT = (unsigned short*)(skipc + (size_t)N_NODES * DIM); // [448,64]
    float* ball   = (float*)(WallT + NCOL * 64);             // [448]
    int* bincnt   = (int*)(ball + NCOL);                     // [256]
    unsigned* bins = (unsigned*)(bincnt + 256);              // [NBIN*BCAP]
    int* deg      = (int*)(bins + (size_t)NBIN * BCAP);      // [N]
    unsigned short* elist = (unsigned short*)(deg + N_NODES); // [N*64] u16 ELL

    hipMemsetAsync(bincnt, 0, 256 * sizeof(int), stream);
    hipLaunchKernelGGL(k_pb, dim3(PREP_B + BIN_BLKS), dim3(256), 0, stream,
                       ei, Wq, bq, Wk, bk, Wv, bv, Wsk, bsk, Wc, bc,
                       WallT, ball, bincnt, bins, sacc);
    hipLaunchKernelGGL(k_proj, dim3(PROJ_B), dim3(256), 0, stream,
                       x, WallT, ball, q, kv, skipc);
    hipLaunchKernelGGL(k_ell, dim3(NBIN), dim3(256), 0, stream,
                       bincnt, bins, deg, elist);
    hipLaunchKernelGGL(k_attn, dim3(ATTN_B), dim3(256), 0, stream,
                       q, kv, skipc, deg, elist, out, sacc);
    hipLaunchKernelGGL(k_norm, dim3(N_NODES * DIM / 4 / 256 + 1), dim3(256), 0, stream,
                       out, sacc, gamma, beta);
}

// Round 13
// 169.571 us; speedup vs baseline: 1.0618x; 1.0618x over previous
//
#include <hip/hip_runtime.h>
#include <hip/hip_bf16.h>

#define N_NODES 50000
#define N_EDGES 800000
#define DIM 64
#define NHEAD 2
#define HD 128     // NHEAD * DIM
#define NCOL 448   // 128 q + 128 k + 128 vc + 64 skipc
#define MAXDEG 64  // ELL row stride; max Poisson(16) deg over 50k nodes ~ 45

#define NBIN 196    // bins of 256 nodes: 196*256 = 50176 >= 50000
#define BCAP 6144   // bin capacity; lambda=4082, +32 sigma
#define ACH 2048    // edges per bin-block
#define BIN_BLKS 391 // ceil(800000/2048)

#define PREP_B 112  // 448*64/256
#define PROJ_B 782  // ceil(50000/64)
#define ATTN_B 3125 // 50000/16 — 4 nodes per wave, 16 lanes (2 edge-slots x 8 ch) per node

// q pre-scale: 1/sqrt(64) * 1/ln(2)  -> logits are in exp2 domain
#define QSCALE 0.18033688011112042f

typedef short bf16x8 __attribute__((ext_vector_type(8)));
typedef float f32x16 __attribute__((ext_vector_type(16)));
typedef float f32x2 __attribute__((ext_vector_type(2)));

__device__ __forceinline__ unsigned short f2bf(float f) {
    unsigned u = __float_as_uint(f);
    unsigned r = (u + 0x7fffu + ((u >> 16) & 1u)) >> 16;   // RNE
    return (unsigned short)r;
}
// fp8 e4m3 HW converts (gfx950 OCP): encode f32 -> 1 byte
__device__ __forceinline__ unsigned char f2fp8(float f) {
    int r = __builtin_amdgcn_cvt_pk_fp8_f32(f, f, 0, false);
    return (unsigned char)(r & 0xff);
}
// packed bf16 pair (u32) -> f32x2
__device__ __forceinline__ f32x2 bf2x2(unsigned v) {
    f32x2 r;
    r[0] = __uint_as_float(v << 16);
    r[1] = __uint_as_float(v & 0xffff0000u);
    return r;
}
// x + dpp_shuffled(x): pure-VALU cross-lane add (no ds_bpermute / lgkmcnt)
template <int CTRL>
__device__ __forceinline__ float dppadd(float x) {
    int m = __builtin_amdgcn_update_dpp(0, __float_as_int(x), CTRL, 0xf, 0xf, true);
    return x + __int_as_float(m);
}

// ------- merged: folded-weight prep ∥ streamlined edge binning -------
__global__ __launch_bounds__(256) void k_pb(
    const int* __restrict__ ei,
    const float* __restrict__ Wq, const float* __restrict__ bq,
    const float* __restrict__ Wk, const float* __restrict__ bk,
    const float* __restrict__ Wv, const float* __restrict__ bv,
    const float* __restrict__ Wskip, const float* __restrict__ bskip,
    const float* __restrict__ Wc, const float* __restrict__ bc,
    unsigned short* __restrict__ WallT, float* __restrict__ ball,
    int* __restrict__ bincnt, unsigned* __restrict__ bins,
    double* __restrict__ sacc)
{
    const int t = threadIdx.x;
    if (blockIdx.x < PREP_B) {
        if (blockIdx.x == 0) { sacc[t] = 0.0; sacc[256 + t] = 0.0; }
        int gid = blockIdx.x * 256 + t;   // 0..28671
        const int j = gid >> 6;   // output column 0..447
        const int d = gid & 63;   // k index
        float w, bb;
        if (j < 128) {
            w = Wq[d * HD + j] * QSCALE;
            bb = bq[j] * QSCALE;
        } else if (j < 256) {
            int jj = j - 128;
            w = Wk[d * HD + jj];
            bb = bk[jj];
        } else if (j < 384) {
            int jj = j - 256;
            int h = jj >> 6, jc = jj & 63;
            float s = 0.f, sb = 0.f;
            for (int c = 0; c < 64; c++) {
                float wc = Wc[(h * 64 + c) * DIM + jc];
                s  += Wv[d * HD + h * 64 + c] * wc;
                sb += bv[h * 64 + c] * wc;
            }
            w = s; bb = sb;
        } else {
            int jj = j - 384;
            float s = 0.f, sb = bc[jj];
            for (int c = 0; c < HD; c++) {
                float wc = Wc[c * DIM + jj];
                s  += Wskip[d * HD + c] * wc;
                sb += bskip[c] * wc;
            }
            w = s; bb = sb;
        }
        WallT[gid] = f2bf(w);
        if (d == 0) ball[j] = bb;
        return;
    }
    // ---- binning: count+rank, reserve, scatter ----
    __shared__ int hist[256];
    __shared__ int gbase[256];
    const int e0 = (blockIdx.x - PREP_B) * ACH;
    hist[t] = 0;
    __syncthreads();
    unsigned pk8[8];
    int bin8[8], sl8[8];
#pragma unroll
    for (int k = 0; k < 8; k++) {
        int e = e0 + t + k * 256;
        if (e < N_EDGES) {
            int src = ei[e];
            int d = ei[N_EDGES + e];
            int bin = d >> 8;
            pk8[k] = (unsigned)(((d & 255) << 16) | src);
            bin8[k] = bin;
            sl8[k] = atomicAdd(&hist[bin], 1);
        } else {
            bin8[k] = -1;
        }
    }
    __syncthreads();
    if (t < NBIN) {
        int h = hist[t];
        if (h > 0) gbase[t] = atomicAdd(&bincnt[t], h);
    }
    __syncthreads();
#pragma unroll
    for (int k = 0; k < 8; k++) {
        int bin = bin8[k];
        if (bin >= 0) {
            int pos = gbase[bin] + sl8[k];
            if (pos < BCAP) bins[(size_t)bin * BCAP + pos] = pk8[k];
        }
    }
}

// ------- merged: MFMA projection GEMM (LDS-staged coalesced stores) ∥ bin->ELL ------
// q written as bf16 [N,128]. LDS 48KB.
__global__ __launch_bounds__(256) void k_ep(
    const float* __restrict__ x,
    const unsigned short* __restrict__ WallT, const float* __restrict__ ball,
    unsigned short* __restrict__ q, unsigned char* __restrict__ kv,
    float* __restrict__ skipc,
    const int* __restrict__ bincnt, const unsigned* __restrict__ bins,
    int* __restrict__ deg, unsigned short* __restrict__ elist)
{
    __shared__ __align__(16) unsigned char smem[49152];
    const int blk = blockIdx.x;
    const int t = threadIdx.x;
    if (blk >= PROJ_B) {
        const int bin = blk - PROJ_B;
        int* nodecnt = (int*)smem;
        nodecnt[t] = 0;
        __syncthreads();
        int cnt = bincnt[bin]; if (cnt > BCAP) cnt = BCAP;
        const unsigned* bp = bins + (size_t)bin * BCAP;
        for (int i = t; i < cnt; i += 256) {
            unsigned p = bp[i];
            int local = p >> 16;
            int src = p & 0xffff;
            int sl = atomicAdd(&nodecnt[local], 1);
            if (sl < MAXDEG)
                elist[((size_t)((bin << 8) | local)) * MAXDEG + sl] = (unsigned short)src;
        }
        __syncthreads();
        int node = (bin << 8) + t;
        if (node < N_NODES) {
            int dgv = nodecnt[t];
            deg[node] = dgv > MAXDEG ? MAXDEG : dgv;
        }
        return;
    }
    unsigned short* q_s = (unsigned short*)smem;     // [64][128] u16 16KB
    unsigned char* kv_s = smem + 16384;              // [64][256] u8  16KB
    float* sk_s = (float*)(smem + 32768);            // [64][64]  f32 16KB

    const int w = t >> 6;
    const int lane = t & 63;
    const int col = lane & 31;
    const int khalf = lane >> 5;
    const int nloc0 = (w >> 1) * 32;
    const int n0 = blk * 64 + nloc0;
    const int ct0 = (w & 1) * 7;
    const int rowbase = 4 * khalf;

    int nread = n0 + col; if (nread >= N_NODES) nread = N_NODES - 1;
    const float* ap = x + (size_t)nread * 64 + khalf * 8;
    bf16x8 afrag[4];
#pragma unroll
    for (int kk = 0; kk < 4; kk++) {
        float4 xa = *((const float4*)(ap + kk * 16));
        float4 xb4 = *((const float4*)(ap + kk * 16 + 4));
        bf16x8 f;
        f[0] = (short)f2bf(xa.x); f[1] = (short)f2bf(xa.y);
        f[2] = (short)f2bf(xa.z); f[3] = (short)f2bf(xa.w);
        f[4] = (short)f2bf(xb4.x); f[5] = (short)f2bf(xb4.y);
        f[6] = (short)f2bf(xb4.z); f[7] = (short)f2bf(xb4.w);
        afrag[kk] = f;
    }

    for (int tt = 0; tt < 7; tt++) {
        const int gc = (ct0 + tt) * 32 + col;
        const float b = ball[gc];
        f32x16 acc;
#pragma unroll
        for (int r = 0; r < 16; r++) acc[r] = b;
        const unsigned short* bp = WallT + (size_t)gc * 64 + khalf * 8;
#pragma unroll
        for (int kk = 0; kk < 4; kk++) {
            bf16x8 bfrag = *((const bf16x8*)(bp + kk * 16));
            acc = __builtin_amdgcn_mfma_f32_32x32x16_bf16(afrag[kk], bfrag, acc, 0, 0, 0);
        }
        if (gc < 128) {
#pragma unroll
            for (int r = 0; r < 16; r++) {
                int nl = nloc0 + rowbase + (r & 3) + 8 * (r >> 2);
                q_s[nl * 128 + gc] = f2bf(acc[r]);
            }
        } else if (gc < 384) {
            int ch = gc - 128;           // 0..255 (K: 0..127, V: 128..255)
            int half = ch >> 7;          // 0=K, 1=V
            int cc = ch & 127;
            int h = cc >> 6, c = cc & 63;
            int pos = half * 128 + ((c >> 3) << 4) + (h << 3) + (c & 7);
#pragma unroll
            for (int r = 0; r < 16; r++) {
                int nl = nloc0 + rowbase + (r & 3) + 8 * (r >> 2);
                kv_s[nl * 256 + pos] = f2fp8(acc[r]);
            }
        } else {
            int c = gc - 384;
#pragma unroll
            for (int r = 0; r < 16; r++) {
                int nl = nloc0 + rowbase + (r & 3) + 8 * (r >> 2);
                sk_s[nl * 64 + c] = acc[r];
            }
        }
    }
    __syncthreads();
    // ---- coalesced flush ----
    const size_t nbase = (size_t)blk * 64;
    const int nrem = (int)(N_NODES - nbase);      // >=1 always
    {   // q bf16: [64][128] u16 = 1024 uint4 (16 per node)
        const uint4* s4 = (const uint4*)q_s;
        uint4* g4 = (uint4*)(q + nbase * HD);
        int lim = nrem >= 64 ? 1024 : nrem * 16;
#pragma unroll
        for (int kk = 0; kk < 4; kk++) {
            int i = t + kk * 256;
            if (i < lim) g4[i] = s4[i];
        }
    }
    {   // kv: [64][256] u8 = 1024 uint4 (16 per node)
        const uint4* s4 = (const uint4*)kv_s;
        uint4* g4 = (uint4*)(kv + nbase * 256);
        int lim = nrem >= 64 ? 1024 : nrem * 16;
#pragma unroll
        for (int kk = 0; kk < 4; kk++) {
            int i = t + kk * 256;
            if (i < lim) g4[i] = s4[i];
        }
    }
    {   // skipc: [64][64] f32 = 1024 float4 (16 per node)
        const float4* s4 = (const float4*)sk_s;
        float4* g4 = (float4*)(skipc + nbase * DIM);
        int lim = nrem >= 64 ? 1024 : nrem * 16;
#pragma unroll
        for (int kk = 0; kk < 4; kk++) {
            int i = t + kk * 256;
            if (i < lim) g4[i] = s4[i];
        }
    }
}

// -------- fused attention: 16 lanes/node, tiled-batch gather for MLP --------
// Per 16-edge tile (8 per slot): compute all 8 srcs from in-register ELL row
// (shuffle-only), issue 8 independent K-row loads, compute 8 logits (DPP
// reduce + exp2), then 8 V-row loads + accumulate. 8 outstanding gathers/lane
// vs 2 in the 1-deep prefetch version. Selectors are loop-uniform per i:
// dword = i&1, holder = (b0>>2)+(i>>1); u16 half = e (requester-side extract).
__global__ __launch_bounds__(256) void k_attn(
    const unsigned short* __restrict__ q, const unsigned char* __restrict__ kv,
    const float* __restrict__ skipc,
    const int* __restrict__ deg, const unsigned short* __restrict__ elist,
    float* __restrict__ out, double* __restrict__ sacc)
{
    const int w = threadIdx.x >> 6;
    const int lane = threadIdx.x & 63;
    const int e = (lane >> 3) & 1;   // edge slot 0/1
    const int j = lane & 7;          // channels 8j..8j+7 of each head
    const int n = blockIdx.x * 16 + w * 4 + (lane >> 4);
    const bool nvalid = n < N_NODES;
    const int nn = nvalid ? n : N_NODES - 1;

    // ELL row: lane (lane&15) holds entries 4*(lane&15)..+3 (uint2 = 4 u16)
    const uint2 E = *((const uint2*)(elist + (size_t)nn * MAXDEG + (lane & 15) * 4));
    int dg = nvalid ? deg[nn] : 0;
    if (dg > MAXDEG) dg = MAXDEG;
    int dgmax = dg;   // wave max over 4 nodes
    {
        int o1 = __shfl_xor(dgmax, 16, 64); if (o1 > dgmax) dgmax = o1;
        int o2 = __shfl_xor(dgmax, 32, 64); if (o2 > dgmax) dgmax = o2;
    }

    // q row (bf16): 16 uint4 per row; h0 at index j, h1 at 8+j
    const uint4* qp4 = (const uint4*)(q + (size_t)nn * HD);
    const uint4 Qa = qp4[j], Qb = qp4[8 + j];
    f32x2 q0[4], q1[4];
    q0[0] = bf2x2(Qa.x); q0[1] = bf2x2(Qa.y); q0[2] = bf2x2(Qa.z); q0[3] = bf2x2(Qa.w);
    q1[0] = bf2x2(Qb.x); q1[1] = bf2x2(Qb.y); q1[2] = bf2x2(Qb.z); q1[3] = bf2x2(Qb.w);

    f32x2 acc0[4], acc1[4];
#pragma unroll
    for (int i = 0; i < 4; i++) {
        acc0[i] = (f32x2){0.f, 0.f};
        acc1[i] = (f32x2){0.f, 0.f};
    }
    float l0 = 0.f, l1 = 0.f;

    for (int b0 = 0; b0 < dgmax; b0 += 16) {
        // ---- compute this tile's 8 source indices (shuffle-only) ----
        int srcs[8];
#pragma unroll
        for (int i = 0; i < 8; i++) {
            unsigned dwd = (i & 1) ? E.y : E.x;                 // uniform per i
            int holder = (lane & 48) | ((b0 >> 2) + (i >> 1));  // uniform per i
            int sd = __shfl((int)dwd, holder, 64);
            unsigned v16 = e ? (((unsigned)sd) >> 16) : (((unsigned)sd) & 0xffffu);
            srcs[i] = ((b0 + 2 * i + e) < dg) ? (int)v16 : 0;
        }
        // ---- K batch: 8 independent gathers in flight ----
        uint4 Kb[8];
#pragma unroll
        for (int i = 0; i < 8; i++)
            Kb[i] = ((const uint4*)(kv + (size_t)srcs[i] * 256))[j];
        // ---- logits ----
        float w0s[8], w1s[8];
#pragma unroll
        for (int i = 0; i < 8; i++) {
            const bool valid = (b0 + 2 * i + e) < dg;
            f32x2 p0v = q0[0] * __builtin_amdgcn_cvt_pk_f32_fp8(Kb[i].x, false);
            p0v += q0[1] * __builtin_amdgcn_cvt_pk_f32_fp8(Kb[i].x, true);
            p0v += q0[2] * __builtin_amdgcn_cvt_pk_f32_fp8(Kb[i].y, false);
            p0v += q0[3] * __builtin_amdgcn_cvt_pk_f32_fp8(Kb[i].y, true);
            f32x2 p1v = q1[0] * __builtin_amdgcn_cvt_pk_f32_fp8(Kb[i].z, false);
            p1v += q1[1] * __builtin_amdgcn_cvt_pk_f32_fp8(Kb[i].z, true);
            p1v += q1[2] * __builtin_amdgcn_cvt_pk_f32_fp8(Kb[i].w, false);
            p1v += q1[3] * __builtin_amdgcn_cvt_pk_f32_fp8(Kb[i].w, true);
            float p0 = p0v[0] + p0v[1];
            float p1 = p1v[0] + p1v[1];
            p0 = dppadd<0xB1>(p0);  p1 = dppadd<0xB1>(p1);
            p0 = dppadd<0x4E>(p0);  p1 = dppadd<0x4E>(p1);
            p0 = dppadd<0x141>(p0); p1 = dppadd<0x141>(p1);
            w0s[i] = valid ? __builtin_amdgcn_exp2f(p0) : 0.f;
            w1s[i] = valid ? __builtin_amdgcn_exp2f(p1) : 0.f;
            l0 += w0s[i]; l1 += w1s[i];
        }
        // ---- V batch: 8 independent gathers in flight ----
        uint4 Vb[8];
#pragma unroll
        for (int i = 0; i < 8; i++)
            Vb[i] = ((const uint4*)(kv + (size_t)srcs[i] * 256))[8 + j];
#pragma unroll
        for (int i = 0; i < 8; i++) {
            f32x2 w0v = {w0s[i], w0s[i]}, w1v = {w1s[i], w1s[i]};
            acc0[0] += w0v * __builtin_amdgcn_cvt_pk_f32_fp8(Vb[i].x, false);
            acc0[1] += w0v * __builtin_amdgcn_cvt_pk_f32_fp8(Vb[i].x, true);
            acc0[2] += w0v * __builtin_amdgcn_cvt_pk_f32_fp8(Vb[i].y, false);
            acc0[3] += w0v * __builtin_amdgcn_cvt_pk_f32_fp8(Vb[i].y, true);
            acc1[0] += w1v * __builtin_amdgcn_cvt_pk_f32_fp8(Vb[i].z, false);
            acc1[1] += w1v * __builtin_amdgcn_cvt_pk_f32_fp8(Vb[i].z, true);
            acc1[2] += w1v * __builtin_amdgcn_cvt_pk_f32_fp8(Vb[i].w, false);
            acc1[3] += w1v * __builtin_amdgcn_cvt_pk_f32_fp8(Vb[i].w, true);
        }
    }

    // ---- merge the two edge slots (lane bit 3) ----
    l0 = dppadd<0x140>(l0);
    l1 = dppadd<0x140>(l1);
    float* a0 = (float*)acc0;
    float* a1 = (float*)acc1;
#pragma unroll
    for (int i = 0; i < 8; i++) {
        a0[i] += __shfl_xor(a0[i], 8, 64);
        a1[i] += __shfl_xor(a1[i], 8, 64);
    }

    // ---- epilogue: each lane writes its own float4 (slot picks half of 8j..8j+7) ----
    const float inv0 = 1.f / (l0 + 1e-16f), inv1 = 1.f / (l1 + 1e-16f);
    const float4 sk4 = ((const float4*)(skipc + (size_t)nn * DIM))[2 * j + e];
    const int cb = e * 4;
    float o0 = a0[cb + 0] * inv0 + a1[cb + 0] * inv1 + sk4.x;
    float o1 = a0[cb + 1] * inv0 + a1[cb + 1] * inv1 + sk4.y;
    float o2 = a0[cb + 2] * inv0 + a1[cb + 2] * inv1 + sk4.z;
    float o3 = a0[cb + 3] * inv0 + a1[cb + 3] * inv1 + sk4.w;
    if (nvalid) {
        float4 r = {o0, o1, o2, o3};
        ((float4*)(out + (size_t)n * DIM))[2 * j + e] = r;
    }
    // ---- stats: per-lane (s,ss); DPP for levels 1..8, shfl for 16/32 ----
    float s_ = 0.f, ss = 0.f;
    if (nvalid) {
        s_ = o0 + o1 + o2 + o3;
        ss = o0 * o0 + o1 * o1 + o2 * o2 + o3 * o3;
    }
    s_ = dppadd<0xB1>(s_);  ss = dppadd<0xB1>(ss);
    s_ = dppadd<0x4E>(s_);  ss = dppadd<0x4E>(ss);
    s_ = dppadd<0x141>(s_); ss = dppadd<0x141>(ss);
    s_ = dppadd<0x140>(s_); ss = dppadd<0x140>(ss);
    s_ += __shfl_xor(s_, 16, 64);
    ss += __shfl_xor(ss, 16, 64);
    s_ += __shfl_xor(s_, 32, 64);
    ss += __shfl_xor(ss, 32, 64);
    if (lane == 0) {
        int slot = (blockIdx.x * 4 + w) & 255;
        atomicAdd(&sacc[slot], (double)s_);
        atomicAdd(&sacc[256 + slot], (double)ss);
    }
}

// ---------------- graph layernorm + gamma/beta (reduces sacc per block) --------
__global__ __launch_bounds__(256) void k_norm(
    float* __restrict__ out, const double* __restrict__ sacc,
    const float* __restrict__ gamma, const float* __restrict__ beta)
{
    const int t = threadIdx.x;
    __shared__ double red[8];
    double s = sacc[t];
    double ss = sacc[256 + t];
#pragma unroll
    for (int off = 32; off > 0; off >>= 1) {
        s  += __shfl_down(s, off);
        ss += __shfl_down(ss, off);
    }
    int wv = t >> 6;
    if ((t & 63) == 0) { red[wv * 2] = s; red[wv * 2 + 1] = ss; }
    __syncthreads();
    double S  = red[0] + red[2] + red[4] + red[6];
    double SS = red[1] + red[3] + red[5] + red[7];
    const double cnt = (double)N_NODES * (double)DIM;
    double mean = S / cnt;
    double var  = SS / cnt - mean * mean;
    if (var < 0.0) var = 0.0;
    float mf = (float)mean;
    float inv = 1.0f / ((float)sqrt(var) + 1e-5f);
    int i = blockIdx.x * 256 + t;
    if (i >= N_NODES * DIM / 4) return;
    float4 v = ((const float4*)out)[i];
    float4 gv = ((const float4*)gamma)[i & 15];
    float4 bv2 = ((const float4*)beta)[i & 15];
    v.x = (v.x - mf) * inv * gv.x + bv2.x;
    v.y = (v.y - mf) * inv * gv.y + bv2.y;
    v.z = (v.z - mf) * inv * gv.z + bv2.z;
    v.w = (v.w - mf) * inv * gv.w + bv2.w;
    ((float4*)out)[i] = v;
}

extern "C" void kernel_launch(void* const* d_in, const int* in_sizes, int n_in,
                              void* d_out, int out_size, void* d_ws, size_t ws_size,
                              hipStream_t stream) {
    const float* x     = (const float*)d_in[0];
    const int*   ei    = (const int*)d_in[1];
    const float* Wq    = (const float*)d_in[2];
    const float* bq    = (const float*)d_in[3];
    const float* Wk    = (const float*)d_in[4];
    const float* bk    = (const float*)d_in[5];
    const float* Wv    = (const float*)d_in[6];
    const float* bv    = (const float*)d_in[7];
    const float* Wsk   = (const float*)d_in[8];
    const float* bsk   = (const float*)d_in[9];
    const float* Wc    = (const float*)d_in[10];
    const float* bc    = (const float*)d_in[11];
    const float* gamma = (const float*)d_in[12];
    const float* beta  = (const float*)d_in[13];
    float* out = (float*)d_out;

    // ws layout (sacc first for 8B alignment)
    double* sacc = (double*)d_ws;                            // [512] f64 stat slots
    unsigned short* q = (unsigned short*)(sacc + 512);       // [N,128] bf16
    unsigned char* kv = (unsigned char*)(q + (size_t)N_NODES * HD); // [N,256] fp8
    float* skipc = (float*)(kv + (size_t)N_NODES * 256);     // [N,64]  f32
    unsigned short* WallT = (unsigned short*)(skipc + (size_t)N_NODES * DIM); // [448,64]
    float* ball   = (float*)(WallT + NCOL * 64);             // [448]
    int* bincnt   = (int*)(ball + NCOL);                     // [256]
    unsigned* bins = (unsigned*)(bincnt + 256);              // [NBIN*BCAP]
    int* deg      = (int*)(bins + (size_t)NBIN * BCAP);      // [N]
    unsigned short* elist = (unsigned short*)(deg + N_NODES); // [N*64] u16 ELL

    hipMemsetAsync(bincnt, 0, 256 * sizeof(int), stream);
    hipLaunchKernelGGL(k_pb, dim3(PREP_B + BIN_BLKS), dim3(256), 0, stream,
                       ei, Wq, bq, Wk, bk, Wv, bv, Wsk, bsk, Wc, bc,
                       WallT, ball, bincnt, bins, sacc);
    hipLaunchKernelGGL(k_ep, dim3(PROJ_B + NBIN), dim3(256), 0, stream,
                       x, WallT, ball, q, kv, skipc, bincnt, bins, deg, elist);
    hipLaunchKernelGGL(k_attn, dim3(ATTN_B), dim3(256), 0, stream,
                       q, kv, skipc, deg, elist, out, sacc);
    hipLaunchKernelGGL(k_norm, dim3(N_NODES * DIM / 4 / 256 + 1), dim3(256), 0, stream,
                       out, sacc, gamma, beta);
}